// Round 8
// baseline (148.610 us; speedup 1.0000x reference)
//
#include <hip/hip_runtime.h>

#define EPS 1e-5f

typedef _Float16 half4_t __attribute__((ext_vector_type(4)));
typedef _Float16 half8_t __attribute__((ext_vector_type(8)));
typedef float floatx4 __attribute__((ext_vector_type(4)));

__device__ __forceinline__ unsigned short f2hb(float f) {
  _Float16 h = (_Float16)f;
  return __builtin_bit_cast(unsigned short, h);
}
__device__ __forceinline__ float hb2f(unsigned short u) {
  return (float)__builtin_bit_cast(_Float16, u);
}
__device__ __forceinline__ unsigned int pack2(float a, float b) {
  return (unsigned int)f2hb(a) | ((unsigned int)f2hb(b) << 16);
}
struct __attribute__((aligned(4))) F4 {
  float v[4];
};
__device__ __forceinline__ F4 ldg4(const float* p) { return *reinterpret_cast<const F4*>(p); }

// ---------------------------------------------------------------------------
// Kernel 1: qkv[b][o][h] = BN(qkv_w @ x), fp16 MFMA 16x16x32, single-pass.
// ---------------------------------------------------------------------------
__global__ __launch_bounds__(256) void k_qkv_gemm(const float* __restrict__ x,
                                                  const float* __restrict__ W,
                                                  const float* __restrict__ bnq,
                                                  float* __restrict__ qkv) {
  __shared__ unsigned short Ah[64 * 72];  // [m][k] stride 72 (144B rows)
  __shared__ unsigned short Bh[64 * 66];  // [k][n] stride 66 (odd dwords)
  const int tid = threadIdx.x;
  const int lane = tid & 63;
  const int wid = tid >> 6;
  const int wm = (wid >> 1) * 32, wn = (wid & 1) * 32;
  const int n0 = blockIdx.x * 64;
  const int o0 = blockIdx.y * 64;
  const int l15 = lane & 15, kg = lane >> 4;

  floatx4 acc[2][2] = {};

  const int am = tid >> 2, akq = (tid & 3) * 16;
  const int bk = tid >> 2, bn4 = (tid & 3) * 16;

  for (int ko = 0; ko < 256; ko += 64) {
    __syncthreads();
    {  // stage A (W) -> fp16
      unsigned int tp[8];
#pragma unroll
      for (int u = 0; u < 4; ++u) {
        const float4 w4 =
            *reinterpret_cast<const float4*>(&W[(size_t)(o0 + am) * 256 + ko + akq + u * 4]);
        tp[u * 2] = pack2(w4.x, w4.y);
        tp[u * 2 + 1] = pack2(w4.z, w4.w);
      }
      uint4 s0 = {tp[0], tp[1], tp[2], tp[3]};
      uint4 s1 = {tp[4], tp[5], tp[6], tp[7]};
      *reinterpret_cast<uint4*>(&Ah[am * 72 + akq]) = s0;
      *reinterpret_cast<uint4*>(&Ah[am * 72 + akq + 8]) = s1;
    }
    {  // stage B (x) -> fp16
#pragma unroll
      for (int u = 0; u < 4; ++u) {
        const float4 x4 =
            *reinterpret_cast<const float4*>(&x[(size_t)(ko + bk) * 32768 + n0 + bn4 + u * 4]);
        uint2 p;
        p.x = pack2(x4.x, x4.y);
        p.y = pack2(x4.z, x4.w);
        *reinterpret_cast<uint2*>(&Bh[bk * 66 + bn4 + u * 4]) = p;
      }
    }
    __syncthreads();
#pragma unroll
    for (int kk = 0; kk < 64; kk += 32) {
      half8_t af[2], bf[2];
#pragma unroll
      for (int fm = 0; fm < 2; ++fm) {
        const int mrow = wm + fm * 16 + l15;
        af[fm] = *reinterpret_cast<const half8_t*>(&Ah[mrow * 72 + kk + kg * 8]);
      }
#pragma unroll
      for (int fn = 0; fn < 2; ++fn) {
        const int ncol = wn + fn * 16 + l15;
        half8_t bv;
#pragma unroll
        for (int e = 0; e < 8; ++e)
          bv[e] = __builtin_bit_cast(_Float16, Bh[(kk + kg * 8 + e) * 66 + ncol]);
        bf[fn] = bv;
      }
#pragma unroll
      for (int fm = 0; fm < 2; ++fm)
#pragma unroll
        for (int fn = 0; fn < 2; ++fn)
          acc[fm][fn] =
              __builtin_amdgcn_mfma_f32_16x16x32_f16(af[fm], bf[fn], acc[fm][fn], 0, 0, 0);
    }
  }

  const int b = blockIdx.x;
#pragma unroll
  for (int fm = 0; fm < 2; ++fm) {
    float sc[4], sh[4];
#pragma unroll
    for (int reg = 0; reg < 4; ++reg) {
      const int o = o0 + wm + fm * 16 + kg * 4 + reg;
      sc[reg] = bnq[o] / sqrtf(bnq[1536 + o] + EPS);
      sh[reg] = bnq[512 + o] - bnq[1024 + o] * sc[reg];
    }
#pragma unroll
    for (int fn = 0; fn < 2; ++fn) {
      const int h = wn + fn * 16 + l15;
#pragma unroll
      for (int reg = 0; reg < 4; ++reg) {
        const int o = o0 + wm + fm * 16 + kg * 4 + reg;
        qkv[((size_t)b * 512 + o) * 64 + h] = fmaf(acc[fm][fn][reg], sc[reg], sh[reg]);
      }
    }
  }
}

// ---------------------------------------------------------------------------
// Kernel 2: per (b,g) attention, fp16 MFMA.  Arena 51712 B -> 3 blocks/CU.
//  staging strides 24 u16 (48B rows: 2-way max on half4 frag reads)
//  phase 5 rel_v fragments loaded from GLOBAL (L2-hot) with on-the-fly cvt
// ---------------------------------------------------------------------------
#define SKS 24   // qT/kT/rq/rk row stride (halves)
#define M1S 130  // M1/M2 row stride (halves)
#define PS 72    // P / V row stride (halves)
#define PPS 136  // P' row stride (halves)
#define SS 66    // S row stride (floats); col 64 = rowsum

__global__ __launch_bounds__(256) void k_attn(const float* __restrict__ qkv,
                                              const float* __restrict__ rel,
                                              const float* __restrict__ bns,
                                              const float* __restrict__ bno,
                                              float* __restrict__ out) {
  __shared__ __align__(16) char arena[51712];
  // phase 1-2 staging (dead after phase 2):
  unsigned short* qT = reinterpret_cast<unsigned short*>(arena);           // [64][24] 3072
  unsigned short* kT = reinterpret_cast<unsigned short*>(arena + 3072);    // 3072
  unsigned short* rq = reinterpret_cast<unsigned short*>(arena + 6144);    // [128][24] 6144
  unsigned short* rk = reinterpret_cast<unsigned short*>(arena + 12288);   // 6144 ->18432
  // S overlays staging from phase 3 on:
  float* S_s = reinterpret_cast<float*>(arena);                            // [64][66] 16896
  unsigned short* M1 = reinterpret_cast<unsigned short*>(arena + 18432);   // [64][130] 16640
  unsigned short* M2 = reinterpret_cast<unsigned short*>(arena + 35072);   // 16640 ->51712
  // phase 4-5 overlays (M1/M2 dead):
  unsigned short* Pb = reinterpret_cast<unsigned short*>(arena + 18432);   // [64][72] 9216
  unsigned short* Pp = reinterpret_cast<unsigned short*>(arena + 27648);   // [64][136] 17408
  unsigned short* Vb = reinterpret_cast<unsigned short*>(arena + 45056);   // [32][72] 4608

  const int tid = threadIdx.x;
  const int lane = tid & 63;
  const int wid = tid >> 6;
  const int l15 = lane & 15, kg = lane >> 4;
  const int bg = blockIdx.x;
  const int b = bg >> 3, g = bg & 7;
  const float* src = qkv + ((size_t)b * 512 + (size_t)g * 64) * 64;

  const float scA = bns[g] / sqrtf(bns[72 + g] + EPS);
  const float scB = bns[8 + g] / sqrtf(bns[72 + 8 + g] + EPS);
  const float scC = bns[16 + g] / sqrtf(bns[72 + 16 + g] + EPS);
  const float shv = (bns[24 + g] - bns[48 + g] * scA) +
                    (bns[24 + 8 + g] - bns[48 + 8 + g] * scB) +
                    (bns[24 + 16 + g] - bns[48 + 16 + g] * scC);

  // ---- phase 1: stage qT,kT + rq,rk (all row-contiguous writes) ----
  {
    const int i = tid >> 2, c0 = (tid & 3) * 4;
    float qv[4], kv[4];
#pragma unroll
    for (int e = 0; e < 4; ++e) {
      qv[e] = src[(c0 + e) * 64 + i];
      kv[e] = src[(16 + c0 + e) * 64 + i];
    }
    uint2 qp, kp;
    qp.x = pack2(qv[0], qv[1]);
    qp.y = pack2(qv[2], qv[3]);
    kp.x = pack2(kv[0], kv[1]);
    kp.y = pack2(kv[2], kv[3]);
    *reinterpret_cast<uint2*>(&qT[i * SKS + c0]) = qp;
    *reinterpret_cast<uint2*>(&kT[i * SKS + c0]) = kp;
  }
  {
    const int t = tid >> 1, c0 = (tid & 1) * 8;
    unsigned short vq[8], vk[8];
#pragma unroll
    for (int e = 0; e < 8; ++e) {
      vq[e] = (t < 127) ? f2hb(rel[(c0 + e) * 127 + t]) : (unsigned short)0;
      vk[e] = (t < 127) ? f2hb(rel[(16 + c0 + e) * 127 + t]) : (unsigned short)0;
    }
    uint4 wq, wk;
    wq.x = (unsigned int)vq[0] | ((unsigned int)vq[1] << 16);
    wq.y = (unsigned int)vq[2] | ((unsigned int)vq[3] << 16);
    wq.z = (unsigned int)vq[4] | ((unsigned int)vq[5] << 16);
    wq.w = (unsigned int)vq[6] | ((unsigned int)vq[7] << 16);
    wk.x = (unsigned int)vk[0] | ((unsigned int)vk[1] << 16);
    wk.y = (unsigned int)vk[2] | ((unsigned int)vk[3] << 16);
    wk.z = (unsigned int)vk[4] | ((unsigned int)vk[5] << 16);
    wk.w = (unsigned int)vk[6] | ((unsigned int)vk[7] << 16);
    *reinterpret_cast<uint4*>(&rq[t * SKS + c0]) = wq;
    *reinterpret_cast<uint4*>(&rk[t * SKS + c0]) = wk;
  }
  __syncthreads();

  // ---- phase 2: K=16 MFMAs: qk (regs), M1, M2 (LDS, fp16) ----
  floatx4 qkreg[4];
  {
    const half4_t aq = *reinterpret_cast<const half4_t*>(&qT[(wid * 16 + l15) * SKS + kg * 4]);
#pragma unroll
    for (int nt = 0; nt < 4; ++nt) {
      const half4_t bq = *reinterpret_cast<const half4_t*>(&kT[(nt * 16 + l15) * SKS + kg * 4]);
      const floatx4 z = {};
      qkreg[nt] = __builtin_amdgcn_mfma_f32_16x16x16f16(aq, bq, z, 0, 0, 0);
    }
#pragma unroll
    for (int nt = 0; nt < 8; ++nt) {
      const half4_t br = *reinterpret_cast<const half4_t*>(&rq[(nt * 16 + l15) * SKS + kg * 4]);
      const floatx4 z = {};
      const floatx4 cr = __builtin_amdgcn_mfma_f32_16x16x16f16(aq, br, z, 0, 0, 0);
#pragma unroll
      for (int r = 0; r < 4; ++r)
        M1[(wid * 16 + kg * 4 + r) * M1S + nt * 16 + l15] = f2hb(cr[r]);
    }
    const half4_t ak = *reinterpret_cast<const half4_t*>(&kT[(wid * 16 + l15) * SKS + kg * 4]);
#pragma unroll
    for (int nt = 0; nt < 8; ++nt) {
      const half4_t br = *reinterpret_cast<const half4_t*>(&rk[(nt * 16 + l15) * SKS + kg * 4]);
      const floatx4 z = {};
      const floatx4 cr = __builtin_amdgcn_mfma_f32_16x16x16f16(ak, br, z, 0, 0, 0);
#pragma unroll
      for (int r = 0; r < 4; ++r)
        M2[(wid * 16 + kg * 4 + r) * M1S + nt * 16 + l15] = f2hb(cr[r]);
    }
  }
  __syncthreads();

  // ---- phase 3: assemble S (S_s overlays now-dead staging) ----
#pragma unroll
  for (int nt = 0; nt < 4; ++nt) {
    const int j = nt * 16 + l15;
#pragma unroll
    for (int r = 0; r < 4; ++r) {
      const int i = wid * 16 + kg * 4 + r;
      const int d = i - j + 63;  // 0..126
      const float qr = hb2f(M1[i * M1S + d]);
      const float kr = hb2f(M2[j * M1S + 126 - d]);
      S_s[i * SS + j] = fmaf(scA, qkreg[nt][r], fmaf(scB, qr, fmaf(scC, kr, shv)));
    }
  }
  __syncthreads();

  // ---- phase 4: softmax -> Pb + Pp (scatter + zero complement); stage V ----
  {
    const int i = tid >> 2, sub = tid & 3;
    const float* row = S_s + i * SS + sub * 16;
    float ev[16];
#pragma unroll
    for (int p = 0; p < 8; ++p) {
      const float2 v2 = *reinterpret_cast<const float2*>(row + p * 2);
      ev[p * 2] = v2.x;
      ev[p * 2 + 1] = v2.y;
    }
    float m = ev[0];
#pragma unroll
    for (int jj = 1; jj < 16; ++jj) m = fmaxf(m, ev[jj]);
    m = fmaxf(m, __shfl_xor(m, 1));
    m = fmaxf(m, __shfl_xor(m, 2));
    float sum = 0.f;
#pragma unroll
    for (int jj = 0; jj < 16; ++jj) {
      ev[jj] = __expf(ev[jj] - m);
      sum += ev[jj];
    }
    sum += __shfl_xor(sum, 1);
    sum += __shfl_xor(sum, 2);
    if (sub == 0) S_s[i * SS + 64] = sum;  // rowsum slot
    unsigned int* pw = reinterpret_cast<unsigned int*>(Pb) + i * (PS / 2) + sub * 8;
#pragma unroll
    for (int p = 0; p < 8; ++p) {  // xor-staggered issue order, true columns
      const int pp = p ^ (i & 7);
      pw[pp] = pack2(ev[2 * pp], ev[2 * pp + 1]);
    }
    const int base = i * PPS;
#pragma unroll
    for (int jj = 0; jj < 16; ++jj) {
      const int j = sub * 16 + jj;
      Pp[base + i + 63 - j] = f2hb(ev[jj]);
    }
#pragma unroll
    for (int jj = 0; jj < 16; ++jj) {  // zero complement of [i, i+63]
      const int z = sub * 16 + jj;
      const int t0 = (z < i) ? z : z + 64;
      Pp[base + t0] = 0;
    }
  }
  {
    const int cv = tid >> 3, t8 = tid & 7;
    const float4 a = *reinterpret_cast<const float4*>(&src[(32 + cv) * 64 + t8 * 8]);
    const float4 b2 = *reinterpret_cast<const float4*>(&src[(32 + cv) * 64 + t8 * 8 + 4]);
    uint4 wv;
    wv.x = pack2(a.x, a.y);
    wv.y = pack2(a.z, a.w);
    wv.z = pack2(b2.x, b2.y);
    wv.w = pack2(b2.z, b2.w);
    *reinterpret_cast<uint4*>(&Vb[cv * PS + t8 * 8]) = wv;
  }
  __syncthreads();

  // ---- phase 5: sv / sve MFMAs (fp16 K=32) + BN epilogue ----
  floatx4 sva[2] = {}, svea[2] = {};
#pragma unroll
  for (int kk = 0; kk < 2; ++kk) {
    const half8_t pa =
        *reinterpret_cast<const half8_t*>(&Pb[(wid * 16 + l15) * PS + kk * 32 + kg * 8]);
#pragma unroll
    for (int nt = 0; nt < 2; ++nt) {
      const half8_t vb =
          *reinterpret_cast<const half8_t*>(&Vb[(nt * 16 + l15) * PS + kk * 32 + kg * 8]);
      sva[nt] = __builtin_amdgcn_mfma_f32_16x16x32_f16(pa, vb, sva[nt], 0, 0, 0);
    }
  }
#pragma unroll
  for (int kk = 0; kk < 4; ++kk) {
    const half8_t pp =
        *reinterpret_cast<const half8_t*>(&Pp[(wid * 16 + l15) * PPS + kk * 32 + kg * 8]);
    const int t0 = kk * 32 + kg * 8;
#pragma unroll
    for (int nt = 0; nt < 2; ++nt) {
      const float* rp = rel + (size_t)(32 + nt * 16 + l15) * 127 + t0;
      half8_t rb;
      if (t0 < 120) {  // all 8 t's <= 126
        const F4 a = ldg4(rp);
        const F4 c = ldg4(rp + 4);
#pragma unroll
        for (int e = 0; e < 4; ++e) {
          rb[e] = (_Float16)a.v[e];
          rb[4 + e] = (_Float16)c.v[e];
        }
      } else {  // t0 == 120: t = 120..127, zero t==127
#pragma unroll
        for (int e = 0; e < 8; ++e) rb[e] = (_Float16)((t0 + e < 127) ? rp[e] : 0.f);
      }
      svea[nt] = __builtin_amdgcn_mfma_f32_16x16x32_f16(pp, rb, svea[nt], 0, 0, 0);
    }
  }
#pragma unroll
  for (int nt = 0; nt < 2; ++nt) {
    const int c = nt * 16 + l15;
    const int ch = ((g << 5) + c) * 2;
    const float sc0 = bno[ch] / sqrtf(bno[1536 + ch] + EPS);
    const float sh0 = bno[512 + ch] - bno[1024 + ch] * sc0;
    const float sc1 = bno[ch + 1] / sqrtf(bno[1536 + ch + 1] + EPS);
    const float sh1 = bno[512 + ch + 1] - bno[1024 + ch + 1] * sc1;
#pragma unroll
    for (int r = 0; r < 4; ++r) {
      const int i = wid * 16 + kg * 4 + r;
      const float inv = 1.0f / S_s[i * SS + 64];
      const float val = fmaf(sc0, sva[nt][r] * inv, sh0) + fmaf(sc1, svea[nt][r] * inv, sh1);
      S_s[c * SS + i] = val;  // out-tile [c][i]; col 64 (rowsum) untouched
    }
  }
  __syncthreads();
  {
    const size_t outbase = (size_t)b * 64;
#pragma unroll
    for (int r = 0; r < 8; ++r) {
      const int idx = tid + r * 256;
      const int cc = idx >> 6, ii = idx & 63;
      out[(size_t)((g << 5) + cc) * 32768 + outbase + ii] = S_s[cc * SS + ii];
    }
  }
}

extern "C" void kernel_launch(void* const* d_in, const int* in_sizes, int n_in,
                              void* d_out, int out_size, void* d_ws, size_t ws_size,
                              hipStream_t stream) {
  const float* x = (const float*)d_in[0];         // (1,256,16,32,64)
  const float* qkv_w = (const float*)d_in[1];     // (512,256)
  const float* relative = (const float*)d_in[2];  // (64,127)
  const float* bn_qkv = (const float*)d_in[3];    // (4,512)
  const float* bn_sim = (const float*)d_in[4];    // (4,24)
  const float* bn_out = (const float*)d_in[5];    // (4,512)
  float* out = (float*)d_out;                     // (256, 512, 64) as [op][b][h]
  float* qkv = (float*)d_ws;                      // 64 MB scratch

  k_qkv_gemm<<<dim3(512, 8), 256, 0, stream>>>(x, qkv_w, bn_qkv, qkv);
  k_attn<<<4096, 256, 0, stream>>>(qkv, relative, bn_sim, bn_out, out);
}

// Round 9
// 114.113 us; speedup vs baseline: 1.3023x; 1.3023x over previous
//
#include <hip/hip_runtime.h>

#define EPS 1e-5f

typedef _Float16 half4_t __attribute__((ext_vector_type(4)));
typedef _Float16 half8_t __attribute__((ext_vector_type(8)));
typedef float floatx4 __attribute__((ext_vector_type(4)));

__device__ __forceinline__ unsigned short f2hb(float f) {
  _Float16 h = (_Float16)f;
  return __builtin_bit_cast(unsigned short, h);
}
__device__ __forceinline__ float hb2f(unsigned short u) {
  return (float)__builtin_bit_cast(_Float16, u);
}
__device__ __forceinline__ unsigned int pack2(float a, float b) {
  return (unsigned int)f2hb(a) | ((unsigned int)f2hb(b) << 16);
}

// ws layout (bytes):
//   qkv_h (fp16, v rows only used): [512 b][512 o][64 h]        @ 0        (33,554,432)
//   qkT   (fp16): [512 b][8 g][64 h][32 c]                      @ 33554432 (16,777,216)
//   relTq (fp16): [128 t][16 c]                                 @ 50331648 (4096)
//   relTk (fp16): [128 t][16 c]                                 @ 50335744 (4096)
//   relV  (fp16): [32 c][128 t]                                 @ 50339840 (8192)
//   bnsF  (f32) : [8 g][4]                                      @ 50348032 (128)
//   bnoSc (f32) : [512]                                         @ 50348160 (2048)
//   bnoSh (f32) : [512]                                         @ 50350208 (2048)
#define WS_QKT 33554432
#define WS_RELTQ 50331648
#define WS_RELTK 50335744
#define WS_RELV 50339840
#define WS_BNSF 50348032
#define WS_BNOSC 50348160
#define WS_BNOSH 50350208

// ---------------------------------------------------------------------------
// Kernel 0: precompute fp16 rel tables (fragment layouts) + folded BN coeffs
// ---------------------------------------------------------------------------
__global__ __launch_bounds__(256) void k_setup(const float* __restrict__ rel,
                                               const float* __restrict__ bns,
                                               const float* __restrict__ bno,
                                               char* __restrict__ ws) {
  unsigned short* relTq = (unsigned short*)(ws + WS_RELTQ);
  unsigned short* relTk = (unsigned short*)(ws + WS_RELTK);
  unsigned short* relV = (unsigned short*)(ws + WS_RELV);
  float* bnsF = (float*)(ws + WS_BNSF);
  float* bnoSc = (float*)(ws + WS_BNOSC);
  float* bnoSh = (float*)(ws + WS_BNOSH);
  const int tid = threadIdx.x;
  for (int idx = tid; idx < 2048; idx += 256) {
    const int t = idx >> 4, c = idx & 15;
    relTq[idx] = (t < 127) ? f2hb(rel[c * 127 + t]) : (unsigned short)0;
    relTk[idx] = (t < 127) ? f2hb(rel[(16 + c) * 127 + t]) : (unsigned short)0;
  }
  for (int idx = tid; idx < 4096; idx += 256) {
    const int c = idx >> 7, t = idx & 127;
    relV[idx] = (t < 127) ? f2hb(rel[(32 + c) * 127 + t]) : (unsigned short)0;
  }
  if (tid < 8) {
    const int g = tid;
    const float scA = bns[g] / sqrtf(bns[72 + g] + EPS);
    const float scB = bns[8 + g] / sqrtf(bns[72 + 8 + g] + EPS);
    const float scC = bns[16 + g] / sqrtf(bns[72 + 16 + g] + EPS);
    const float shv = (bns[24 + g] - bns[48 + g] * scA) +
                      (bns[24 + 8 + g] - bns[48 + 8 + g] * scB) +
                      (bns[24 + 16 + g] - bns[48 + 16 + g] * scC);
    bnsF[g * 4 + 0] = scA;
    bnsF[g * 4 + 1] = scB;
    bnsF[g * 4 + 2] = scC;
    bnsF[g * 4 + 3] = shv;
  }
  for (int idx = tid; idx < 512; idx += 256) {
    const float sc = bno[idx] / sqrtf(bno[1536 + idx] + EPS);
    bnoSc[idx] = sc;
    bnoSh[idx] = bno[512 + idx] - bno[1024 + idx] * sc;
  }
}

// ---------------------------------------------------------------------------
// Kernel 1: qkv = BN(W @ x), fp16 MFMA. q/k rows (o%64<32) -> qkT transposed
// fp16; v rows (o%64>=32) -> qkv_h fp16.
// ---------------------------------------------------------------------------
__global__ __launch_bounds__(256) void k_qkv_gemm(const float* __restrict__ x,
                                                  const float* __restrict__ W,
                                                  const float* __restrict__ bnq,
                                                  char* __restrict__ ws) {
  unsigned short* qkv_h = (unsigned short*)ws;
  unsigned short* qkT = (unsigned short*)(ws + WS_QKT);
  __shared__ unsigned short Ah[64 * 72];
  __shared__ unsigned short Bh[64 * 66];
  const int tid = threadIdx.x;
  const int lane = tid & 63;
  const int wid = tid >> 6;
  const int wm = (wid >> 1) * 32, wn = (wid & 1) * 32;
  const int n0 = blockIdx.x * 64;
  const int g = blockIdx.y;
  const int o0 = g * 64;
  const int l15 = lane & 15, kg = lane >> 4;

  floatx4 acc[2][2] = {};
  const int am = tid >> 2, akq = (tid & 3) * 16;
  const int bk = tid >> 2, bn4 = (tid & 3) * 16;

  for (int ko = 0; ko < 256; ko += 64) {
    __syncthreads();
    {
      unsigned int tp[8];
#pragma unroll
      for (int u = 0; u < 4; ++u) {
        const float4 w4 =
            *reinterpret_cast<const float4*>(&W[(size_t)(o0 + am) * 256 + ko + akq + u * 4]);
        tp[u * 2] = pack2(w4.x, w4.y);
        tp[u * 2 + 1] = pack2(w4.z, w4.w);
      }
      uint4 s0 = {tp[0], tp[1], tp[2], tp[3]};
      uint4 s1 = {tp[4], tp[5], tp[6], tp[7]};
      *reinterpret_cast<uint4*>(&Ah[am * 72 + akq]) = s0;
      *reinterpret_cast<uint4*>(&Ah[am * 72 + akq + 8]) = s1;
    }
    {
#pragma unroll
      for (int u = 0; u < 4; ++u) {
        const float4 x4 =
            *reinterpret_cast<const float4*>(&x[(size_t)(ko + bk) * 32768 + n0 + bn4 + u * 4]);
        uint2 p;
        p.x = pack2(x4.x, x4.y);
        p.y = pack2(x4.z, x4.w);
        *reinterpret_cast<uint2*>(&Bh[bk * 66 + bn4 + u * 4]) = p;
      }
    }
    __syncthreads();
#pragma unroll
    for (int kk = 0; kk < 64; kk += 32) {
      half8_t af[2], bf[2];
#pragma unroll
      for (int fm = 0; fm < 2; ++fm) {
        const int mrow = wm + fm * 16 + l15;
        af[fm] = *reinterpret_cast<const half8_t*>(&Ah[mrow * 72 + kk + kg * 8]);
      }
#pragma unroll
      for (int fn = 0; fn < 2; ++fn) {
        const int ncol = wn + fn * 16 + l15;
        half8_t bv;
#pragma unroll
        for (int e = 0; e < 8; ++e)
          bv[e] = __builtin_bit_cast(_Float16, Bh[(kk + kg * 8 + e) * 66 + ncol]);
        bf[fn] = bv;
      }
#pragma unroll
      for (int fm = 0; fm < 2; ++fm)
#pragma unroll
        for (int fn = 0; fn < 2; ++fn)
          acc[fm][fn] =
              __builtin_amdgcn_mfma_f32_16x16x32_f16(af[fm], bf[fn], acc[fm][fn], 0, 0, 0);
    }
  }

  const size_t b = blockIdx.x;
#pragma unroll
  for (int fm = 0; fm < 2; ++fm) {
    float sc[4], sh[4];
#pragma unroll
    for (int reg = 0; reg < 4; ++reg) {
      const int o = o0 + wm + fm * 16 + kg * 4 + reg;
      sc[reg] = bnq[o] / sqrtf(bnq[1536 + o] + EPS);
      sh[reg] = bnq[512 + o] - bnq[1024 + o] * sc[reg];
    }
#pragma unroll
    for (int fn = 0; fn < 2; ++fn) {
      const int h = wn + fn * 16 + l15;
#pragma unroll
      for (int reg = 0; reg < 4; ++reg) {
        const int row = wm + fm * 16 + kg * 4 + reg;  // o % 64
        const float val = fmaf(acc[fm][fn][reg], sc[reg], sh[reg]);
        if (wm == 0) {  // q/k rows -> transposed qkT
          qkT[((b * 8 + g) * 64 + h) * 32 + row] = f2hb(val);
        } else {  // v rows -> qkv_h
          qkv_h[(b * 512 + o0 + row) * 64 + h] = f2hb(val);
        }
      }
    }
  }
}

// ---------------------------------------------------------------------------
// Kernel 2: per (b,g) attention, fp16 MFMA, in-register softmax.
// Arena 38144 B -> 4 blocks/CU (launch_bounds caps VGPR at 128).
// ---------------------------------------------------------------------------
#define QKS 36   // qkL row stride (halves)
#define M1S 132  // M1/M2 row stride (halves)
#define PBS 72   // Pb / Vb row stride (halves)
#define PPS 136  // Pp row stride (halves)
#define OTS 67   // out-tile row stride (floats)

__global__ __launch_bounds__(256, 4) void k_attn(const char* __restrict__ ws,
                                                 float* __restrict__ out) {
  const unsigned short* qkv_h = (const unsigned short*)ws;
  const unsigned short* qkTg = (const unsigned short*)(ws + WS_QKT);
  const unsigned short* relTq = (const unsigned short*)(ws + WS_RELTQ);
  const unsigned short* relTk = (const unsigned short*)(ws + WS_RELTK);
  const unsigned short* relV = (const unsigned short*)(ws + WS_RELV);
  const float* bnsF = (const float*)(ws + WS_BNSF);
  const float* bnoSc = (const float*)(ws + WS_BNOSC);
  const float* bnoSh = (const float*)(ws + WS_BNOSH);

  __shared__ __align__(16) char arena[38144];
  unsigned short* qkL = (unsigned short*)arena;                    // [64][36]  4608  (ph1-2)
  unsigned short* M1 = (unsigned short*)(arena + 4608);            // [64][132] 16896 (ph2-3a)
  unsigned short* M2 = (unsigned short*)(arena + 21504);           // [64][132] 16896 -> 38400? no: 21504+16896=38400
  // NOTE: arena sized 38400 below via M2 end.
  unsigned short* Pb = (unsigned short*)arena;                     // [64][72]  9216  (ph3b-5)
  unsigned short* Pp = (unsigned short*)(arena + 9216);            // [64][136] 17408
  unsigned short* Vb = (unsigned short*)(arena + 26624);           // [32][72]  4608
  float* Sout = (float*)arena;                                     // [32][67]  8576  (epilogue)

  const int tid = threadIdx.x;
  const int lane = tid & 63;
  const int wid = tid >> 6;
  const int l15 = lane & 15, kg = lane >> 4;
  const int bg = blockIdx.x;
  const int b = bg >> 3, g = bg & 7;

  // ---- phase 1: stage qkT block (64x32 fp16, 4KB) ----
  {
    const uint4 qv = *reinterpret_cast<const uint4*>(&qkTg[(size_t)(((b << 3) + g)) * 2048 + tid * 8]);
    const int i = tid >> 2, c0 = (tid & 3) * 8;
    uint2 lo, hi;
    lo.x = qv.x; lo.y = qv.y; hi.x = qv.z; hi.y = qv.w;
    *reinterpret_cast<uint2*>(&qkL[i * QKS + c0]) = lo;
    *reinterpret_cast<uint2*>(&qkL[i * QKS + c0 + 4]) = hi;
  }
  __syncthreads();

  // ---- phase 2: K=16 MFMAs: qk (regs), M1 = q^T rel_q, M2 = k^T rel_k ----
  floatx4 qkreg[4];
  {
    half4_t brq[8], brk[8];
#pragma unroll
    for (int nt = 0; nt < 8; ++nt) {
      brq[nt] = *reinterpret_cast<const half4_t*>(&relTq[(nt * 16 + l15) * 16 + kg * 4]);
      brk[nt] = *reinterpret_cast<const half4_t*>(&relTk[(nt * 16 + l15) * 16 + kg * 4]);
    }
    const half4_t aq = *reinterpret_cast<const half4_t*>(&qkL[(wid * 16 + l15) * QKS + kg * 4]);
    const half4_t ak =
        *reinterpret_cast<const half4_t*>(&qkL[(wid * 16 + l15) * QKS + 16 + kg * 4]);
#pragma unroll
    for (int nt = 0; nt < 4; ++nt) {
      const half4_t bq =
          *reinterpret_cast<const half4_t*>(&qkL[(nt * 16 + l15) * QKS + 16 + kg * 4]);
      const floatx4 z = {};
      qkreg[nt] = __builtin_amdgcn_mfma_f32_16x16x16f16(aq, bq, z, 0, 0, 0);
    }
#pragma unroll
    for (int nt = 0; nt < 8; ++nt) {
      const floatx4 z = {};
      const floatx4 cr = __builtin_amdgcn_mfma_f32_16x16x16f16(aq, brq[nt], z, 0, 0, 0);
#pragma unroll
      for (int r = 0; r < 4; ++r)
        M1[(wid * 16 + kg * 4 + r) * M1S + nt * 16 + l15] = f2hb(cr[r]);
    }
#pragma unroll
    for (int nt = 0; nt < 8; ++nt) {
      const floatx4 z = {};
      const floatx4 cr = __builtin_amdgcn_mfma_f32_16x16x16f16(ak, brk[nt], z, 0, 0, 0);
#pragma unroll
      for (int r = 0; r < 4; ++r)
        M2[(wid * 16 + kg * 4 + r) * M1S + nt * 16 + l15] = f2hb(cr[r]);
    }
  }
  __syncthreads();

  // ---- phase 3a: gather M1/M2, assemble S in registers; prefetch V ----
  const uint4 vld = *reinterpret_cast<const uint4*>(
      &qkv_h[((size_t)b * 512 + g * 64 + 32 + (tid >> 3)) * 64 + (tid & 7) * 8]);
  float sreg[4][4];
  {
    const float4 bf = *reinterpret_cast<const float4*>(&bnsF[g * 4]);
#pragma unroll
    for (int nt = 0; nt < 4; ++nt) {
      const int j = nt * 16 + l15;
#pragma unroll
      for (int r = 0; r < 4; ++r) {
        const int i = wid * 16 + kg * 4 + r;
        const int d = i - j + 63;  // 0..126
        const float qr = hb2f(M1[i * M1S + d]);
        const float kr = hb2f(M2[j * M1S + 126 - d]);
        sreg[nt][r] = fmaf(bf.x, qkreg[nt][r], fmaf(bf.y, qr, fmaf(bf.z, kr, bf.w)));
      }
    }
  }
  __syncthreads();  // M1/M2 dead; Pb/Pp/Vb overlay live

  // ---- phase 3b: in-register softmax; write Pb, Pp (+zero complement), Vb ----
  float sm[4];
#pragma unroll
  for (int r = 0; r < 4; ++r) {
    float m = fmaxf(fmaxf(sreg[0][r], sreg[1][r]), fmaxf(sreg[2][r], sreg[3][r]));
    m = fmaxf(m, __shfl_xor(m, 1));
    m = fmaxf(m, __shfl_xor(m, 2));
    m = fmaxf(m, __shfl_xor(m, 4));
    m = fmaxf(m, __shfl_xor(m, 8));
    float s = 0.f;
#pragma unroll
    for (int nt = 0; nt < 4; ++nt) {
      sreg[nt][r] = __expf(sreg[nt][r] - m);
      s += sreg[nt][r];
    }
    s += __shfl_xor(s, 1);
    s += __shfl_xor(s, 2);
    s += __shfl_xor(s, 4);
    s += __shfl_xor(s, 8);
    sm[r] = s;
  }
#pragma unroll
  for (int r = 0; r < 4; ++r) {
    const int i = wid * 16 + kg * 4 + r;
#pragma unroll
    for (int nt = 0; nt < 4; ++nt) {
      const int j = nt * 16 + l15;
      const unsigned short pv = f2hb(sreg[nt][r]);
      Pb[i * PBS + j] = pv;
      Pp[i * PPS + i + 63 - j] = pv;
    }
#pragma unroll
    for (int e = 0; e < 4; ++e) {  // zero complement of [i, i+63] in [0,128)
      const int z = l15 * 4 + e;
      const int t = (z < i) ? z : z + 64;
      Pp[i * PPS + t] = 0;
    }
  }
  {
    *reinterpret_cast<uint4*>(&Vb[(tid >> 3) * PBS + (tid & 7) * 8]) = vld;
  }
  __syncthreads();

  // ---- phase 5: sv / sve MFMAs (fp16 K=32) ----
  floatx4 sva[2] = {}, svea[2] = {};
#pragma unroll
  for (int kk = 0; kk < 2; ++kk) {
    const half8_t pa =
        *reinterpret_cast<const half8_t*>(&Pb[(wid * 16 + l15) * PBS + kk * 32 + kg * 8]);
#pragma unroll
    for (int nt = 0; nt < 2; ++nt) {
      const half8_t vb =
          *reinterpret_cast<const half8_t*>(&Vb[(nt * 16 + l15) * PBS + kk * 32 + kg * 8]);
      sva[nt] = __builtin_amdgcn_mfma_f32_16x16x32_f16(pa, vb, sva[nt], 0, 0, 0);
    }
  }
#pragma unroll
  for (int kk = 0; kk < 4; ++kk) {
    const half8_t pp =
        *reinterpret_cast<const half8_t*>(&Pp[(wid * 16 + l15) * PPS + kk * 32 + kg * 8]);
#pragma unroll
    for (int nt = 0; nt < 2; ++nt) {
      const half8_t rb =
          *reinterpret_cast<const half8_t*>(&relV[(nt * 16 + l15) * 128 + kk * 32 + kg * 8]);
      svea[nt] = __builtin_amdgcn_mfma_f32_16x16x32_f16(pp, rb, svea[nt], 0, 0, 0);
    }
  }
  __syncthreads();  // all Pb/Pp/Vb reads done; Sout overlays

  // ---- epilogue: BN (precomputed coeffs) + out-tile + coalesced store ----
#pragma unroll
  for (int nt = 0; nt < 2; ++nt) {
    const int c = nt * 16 + l15;
    const int ch = ((g << 5) + c) * 2;
    const float2 scv = *reinterpret_cast<const float2*>(&bnoSc[ch]);
    const float2 shv = *reinterpret_cast<const float2*>(&bnoSh[ch]);
#pragma unroll
    for (int r = 0; r < 4; ++r) {
      const int i = wid * 16 + kg * 4 + r;
      const float inv = 1.0f / sm[r];
      Sout[c * OTS + i] =
          fmaf(scv.x, sva[nt][r] * inv, shv.x) + fmaf(scv.y, svea[nt][r] * inv, shv.y);
    }
  }
  __syncthreads();
  {
    const size_t outbase = (size_t)b * 64;
#pragma unroll
    for (int r = 0; r < 8; ++r) {
      const int idx = tid + r * 256;
      const int cc = idx >> 6, ii = idx & 63;
      out[(size_t)((g << 5) + cc) * 32768 + outbase + ii] = Sout[cc * OTS + ii];
    }
  }
}

extern "C" void kernel_launch(void* const* d_in, const int* in_sizes, int n_in,
                              void* d_out, int out_size, void* d_ws, size_t ws_size,
                              hipStream_t stream) {
  const float* x = (const float*)d_in[0];         // (1,256,16,32,64)
  const float* qkv_w = (const float*)d_in[1];     // (512,256)
  const float* relative = (const float*)d_in[2];  // (64,127)
  const float* bn_qkv = (const float*)d_in[3];    // (4,512)
  const float* bn_sim = (const float*)d_in[4];    // (4,24)
  const float* bn_out = (const float*)d_in[5];    // (4,512)
  float* out = (float*)d_out;                     // (256, 512, 64) as [op][b][h]
  char* ws = (char*)d_ws;

  k_setup<<<1, 256, 0, stream>>>(relative, bn_sim, bn_out, ws);
  k_qkv_gemm<<<dim3(512, 8), 256, 0, stream>>>(x, qkv_w, bn_qkv, ws);
  k_attn<<<4096, 256, 0, stream>>>(ws, out);
}

// Round 10
// 86.737 us; speedup vs baseline: 1.7133x; 1.3156x over previous
//
#include <hip/hip_runtime.h>

#define EPS 1e-5f

typedef _Float16 half4_t __attribute__((ext_vector_type(4)));
typedef _Float16 half8_t __attribute__((ext_vector_type(8)));
typedef float floatx4 __attribute__((ext_vector_type(4)));

__device__ __forceinline__ unsigned short f2hb(float f) {
  _Float16 h = (_Float16)f;
  return __builtin_bit_cast(unsigned short, h);
}
__device__ __forceinline__ float hb2f(unsigned short u) {
  return (float)__builtin_bit_cast(_Float16, u);
}
__device__ __forceinline__ unsigned int pack2(float a, float b) {
  return (unsigned int)f2hb(a) | ((unsigned int)f2hb(b) << 16);
}

// ws layout (bytes):
//   qkv_h (fp16, v rows used): [512 b][512 o][64 h]             @ 0        (33,554,432)
//   qkT   (fp16): [512 b][8 g][64 h][32 c]                      @ 33554432 (16,777,216)
//   relTq (fp16): [128 t][16 c]                                 @ 50331648 (4096)
//   relTk (fp16): [128 t][16 c]                                 @ 50335744 (4096)
//   relV  (fp16): [32 c][128 t]                                 @ 50339840 (8192)
//   bnsF  (f32) : [8 g][4]                                      @ 50348032 (128)
//   bnoSc (f32) : [512]                                         @ 50348160 (2048)
//   bnoSh (f32) : [512]                                         @ 50350208 (2048)
#define WS_QKT 33554432
#define WS_RELTQ 50331648
#define WS_RELTK 50335744
#define WS_RELV 50339840
#define WS_BNSF 50348032
#define WS_BNOSC 50348160
#define WS_BNOSH 50350208

// ---------------------------------------------------------------------------
// Kernel 1: qkv = BN(W @ x), fp16 MFMA.
//  - XCD-local block decode: 8 o-groups sharing an x-slice are 8 bids apart
//    (same XCD under bid%8 round-robin) -> x L2-resident, fetched ~once.
//  - q/k rows -> LDS transpose -> coalesced uint4 stores to qkT.
//  - v rows -> qkv_h fp16 (h-contiguous 2B stores, HW-merged).
//  - block 0 also precomputes rel tables + folded BN coeffs (k_setup folded).
// ---------------------------------------------------------------------------
__global__ __launch_bounds__(256) void k_qkv_gemm(const float* __restrict__ x,
                                                  const float* __restrict__ W,
                                                  const float* __restrict__ bnq,
                                                  const float* __restrict__ rel,
                                                  const float* __restrict__ bns,
                                                  const float* __restrict__ bno,
                                                  char* __restrict__ ws) {
  unsigned short* qkv_h = (unsigned short*)ws;
  unsigned short* qkT = (unsigned short*)(ws + WS_QKT);
  __shared__ unsigned short Ah[64 * 72];
  __shared__ unsigned short Bh[64 * 66];
  const int tid = threadIdx.x;

  // ---- folded setup (block 0 only) ----
  if (blockIdx.x == 0) {
    unsigned short* relTq = (unsigned short*)(ws + WS_RELTQ);
    unsigned short* relTk = (unsigned short*)(ws + WS_RELTK);
    unsigned short* relV = (unsigned short*)(ws + WS_RELV);
    float* bnsF = (float*)(ws + WS_BNSF);
    float* bnoSc = (float*)(ws + WS_BNOSC);
    float* bnoSh = (float*)(ws + WS_BNOSH);
    for (int idx = tid; idx < 2048; idx += 256) {
      const int t = idx >> 4, c = idx & 15;
      relTq[idx] = (t < 127) ? f2hb(rel[c * 127 + t]) : (unsigned short)0;
      relTk[idx] = (t < 127) ? f2hb(rel[(16 + c) * 127 + t]) : (unsigned short)0;
    }
    for (int idx = tid; idx < 4096; idx += 256) {
      const int c = idx >> 7, t = idx & 127;
      relV[idx] = (t < 127) ? f2hb(rel[(32 + c) * 127 + t]) : (unsigned short)0;
    }
    if (tid < 8) {
      const int g = tid;
      const float scA = bns[g] / sqrtf(bns[72 + g] + EPS);
      const float scB = bns[8 + g] / sqrtf(bns[72 + 8 + g] + EPS);
      const float scC = bns[16 + g] / sqrtf(bns[72 + 16 + g] + EPS);
      const float shv = (bns[24 + g] - bns[48 + g] * scA) +
                        (bns[24 + 8 + g] - bns[48 + 8 + g] * scB) +
                        (bns[24 + 16 + g] - bns[48 + 16 + g] * scC);
      bnsF[g * 4 + 0] = scA;
      bnsF[g * 4 + 1] = scB;
      bnsF[g * 4 + 2] = scC;
      bnsF[g * 4 + 3] = shv;
    }
    for (int idx = tid; idx < 512; idx += 256) {
      const float sc = bno[idx] / sqrtf(bno[1536 + idx] + EPS);
      bnoSc[idx] = sc;
      bnoSh[idx] = bno[512 + idx] - bno[1024 + idx] * sc;
    }
  }

  // ---- XCD-local decode ----
  const int raw = blockIdx.x;
  const int xcd = raw & 7;
  const int seq = raw >> 3;
  const int g = seq & 7;            // 8 o-groups consecutive on one XCD
  const int nb_local = seq >> 3;    // 0..63
  const int bidx_n = xcd * 64 + nb_local;
  const int n0 = bidx_n * 64;
  const int o0 = g * 64;
  const size_t b = bidx_n;

  const int lane = tid & 63;
  const int wid = tid >> 6;
  const int wm = (wid >> 1) * 32, wn = (wid & 1) * 32;
  const int l15 = lane & 15, kg = lane >> 4;

  floatx4 acc[2][2] = {};
  const int am = tid >> 2, akq = (tid & 3) * 16;
  const int bk = tid >> 2, bn4 = (tid & 3) * 16;

  for (int ko = 0; ko < 256; ko += 64) {
    __syncthreads();
    {
      unsigned int tp[8];
#pragma unroll
      for (int u = 0; u < 4; ++u) {
        const float4 w4 =
            *reinterpret_cast<const float4*>(&W[(size_t)(o0 + am) * 256 + ko + akq + u * 4]);
        tp[u * 2] = pack2(w4.x, w4.y);
        tp[u * 2 + 1] = pack2(w4.z, w4.w);
      }
      uint4 s0 = {tp[0], tp[1], tp[2], tp[3]};
      uint4 s1 = {tp[4], tp[5], tp[6], tp[7]};
      *reinterpret_cast<uint4*>(&Ah[am * 72 + akq]) = s0;
      *reinterpret_cast<uint4*>(&Ah[am * 72 + akq + 8]) = s1;
    }
    {
#pragma unroll
      for (int u = 0; u < 4; ++u) {
        const float4 x4 =
            *reinterpret_cast<const float4*>(&x[(size_t)(ko + bk) * 32768 + n0 + bn4 + u * 4]);
        uint2 p;
        p.x = pack2(x4.x, x4.y);
        p.y = pack2(x4.z, x4.w);
        *reinterpret_cast<uint2*>(&Bh[bk * 66 + bn4 + u * 4]) = p;
      }
    }
    __syncthreads();
#pragma unroll
    for (int kk = 0; kk < 64; kk += 32) {
      half8_t af[2], bf[2];
#pragma unroll
      for (int fm = 0; fm < 2; ++fm) {
        const int mrow = wm + fm * 16 + l15;
        af[fm] = *reinterpret_cast<const half8_t*>(&Ah[mrow * 72 + kk + kg * 8]);
      }
#pragma unroll
      for (int fn = 0; fn < 2; ++fn) {
        const int ncol = wn + fn * 16 + l15;
        half8_t bv;
#pragma unroll
        for (int e = 0; e < 8; ++e)
          bv[e] = __builtin_bit_cast(_Float16, Bh[(kk + kg * 8 + e) * 66 + ncol]);
        bf[fn] = bv;
      }
#pragma unroll
      for (int fm = 0; fm < 2; ++fm)
#pragma unroll
        for (int fn = 0; fn < 2; ++fn)
          acc[fm][fn] =
              __builtin_amdgcn_mfma_f32_16x16x32_f16(af[fm], bf[fn], acc[fm][fn], 0, 0, 0);
    }
  }

  // ---- epilogue: BN; q/k -> LDS transpose; v -> direct fp16 stores ----
  __syncthreads();                   // protect Ah before reuse
  unsigned short* Tq = Ah;           // [32 row][66 h] u16 (4224 B)
#pragma unroll
  for (int fm = 0; fm < 2; ++fm) {
    float sc[4], sh[4];
#pragma unroll
    for (int reg = 0; reg < 4; ++reg) {
      const int o = o0 + wm + fm * 16 + kg * 4 + reg;
      sc[reg] = bnq[o] / sqrtf(bnq[1536 + o] + EPS);
      sh[reg] = bnq[512 + o] - bnq[1024 + o] * sc[reg];
    }
#pragma unroll
    for (int fn = 0; fn < 2; ++fn) {
      const int h = wn + fn * 16 + l15;
#pragma unroll
      for (int reg = 0; reg < 4; ++reg) {
        const int row = wm + fm * 16 + kg * 4 + reg;  // o % 64
        const float val = fmaf(acc[fm][fn][reg], sc[reg], sh[reg]);
        if (wm == 0) {
          Tq[(row & 31) * 66 + h] = f2hb(val);  // q/k rows 0..31
        } else {
          qkv_h[(b * 512 + o0 + row) * 64 + h] = f2hb(val);  // v rows 32..63
        }
      }
    }
  }
  __syncthreads();
  {  // cooperative coalesced qkT store: [h][32 c], one uint4 per thread
    const int h = tid >> 2, c0 = (tid & 3) * 8;
    unsigned short tmp[8];
#pragma unroll
    for (int e = 0; e < 8; ++e) tmp[e] = Tq[(c0 + e) * 66 + h];
    uint4 wv;
    wv.x = (unsigned int)tmp[0] | ((unsigned int)tmp[1] << 16);
    wv.y = (unsigned int)tmp[2] | ((unsigned int)tmp[3] << 16);
    wv.z = (unsigned int)tmp[4] | ((unsigned int)tmp[5] << 16);
    wv.w = (unsigned int)tmp[6] | ((unsigned int)tmp[7] << 16);
    *reinterpret_cast<uint4*>(&qkT[((b * 8 + g) * 64 + h) * 32 + c0]) = wv;
  }
}

// ---------------------------------------------------------------------------
// Kernel 2: per (b,g) attention, fp16 MFMA, in-register softmax. (r9, unchanged)
// ---------------------------------------------------------------------------
#define QKS 36   // qkL row stride (halves)
#define M1S 132  // M1/M2 row stride (halves)
#define PBS 72   // Pb / Vb row stride (halves)
#define PPS 136  // Pp row stride (halves)
#define OTS 67   // out-tile row stride (floats)

__global__ __launch_bounds__(256, 4) void k_attn(const char* __restrict__ ws,
                                                 float* __restrict__ out) {
  const unsigned short* qkv_h = (const unsigned short*)ws;
  const unsigned short* qkTg = (const unsigned short*)(ws + WS_QKT);
  const unsigned short* relTq = (const unsigned short*)(ws + WS_RELTQ);
  const unsigned short* relTk = (const unsigned short*)(ws + WS_RELTK);
  const unsigned short* relV = (const unsigned short*)(ws + WS_RELV);
  const float* bnsF = (const float*)(ws + WS_BNSF);
  const float* bnoSc = (const float*)(ws + WS_BNOSC);
  const float* bnoSh = (const float*)(ws + WS_BNOSH);

  __shared__ __align__(16) char arena[38400];
  unsigned short* qkL = (unsigned short*)arena;                    // [64][36]  4608  (ph1-2)
  unsigned short* M1 = (unsigned short*)(arena + 4608);            // [64][132] 16896 (ph2-3a)
  unsigned short* M2 = (unsigned short*)(arena + 21504);           // [64][132] 16896
  unsigned short* Pb = (unsigned short*)arena;                     // [64][72]  9216  (ph3b-5)
  unsigned short* Pp = (unsigned short*)(arena + 9216);            // [64][136] 17408
  unsigned short* Vb = (unsigned short*)(arena + 26624);           // [32][72]  4608
  float* Sout = (float*)arena;                                     // [32][67]  8576  (epilogue)

  const int tid = threadIdx.x;
  const int lane = tid & 63;
  const int wid = tid >> 6;
  const int l15 = lane & 15, kg = lane >> 4;
  const int bg = blockIdx.x;
  const int b = bg >> 3, g = bg & 7;

  // ---- phase 1: stage qkT block (64x32 fp16, 4KB) ----
  {
    const uint4 qv =
        *reinterpret_cast<const uint4*>(&qkTg[(size_t)(((b << 3) + g)) * 2048 + tid * 8]);
    const int i = tid >> 2, c0 = (tid & 3) * 8;
    uint2 lo, hi;
    lo.x = qv.x; lo.y = qv.y; hi.x = qv.z; hi.y = qv.w;
    *reinterpret_cast<uint2*>(&qkL[i * QKS + c0]) = lo;
    *reinterpret_cast<uint2*>(&qkL[i * QKS + c0 + 4]) = hi;
  }
  __syncthreads();

  // ---- phase 2: K=16 MFMAs: qk (regs), M1 = q^T rel_q, M2 = k^T rel_k ----
  floatx4 qkreg[4];
  {
    half4_t brq[8], brk[8];
#pragma unroll
    for (int nt = 0; nt < 8; ++nt) {
      brq[nt] = *reinterpret_cast<const half4_t*>(&relTq[(nt * 16 + l15) * 16 + kg * 4]);
      brk[nt] = *reinterpret_cast<const half4_t*>(&relTk[(nt * 16 + l15) * 16 + kg * 4]);
    }
    const half4_t aq = *reinterpret_cast<const half4_t*>(&qkL[(wid * 16 + l15) * QKS + kg * 4]);
    const half4_t ak =
        *reinterpret_cast<const half4_t*>(&qkL[(wid * 16 + l15) * QKS + 16 + kg * 4]);
#pragma unroll
    for (int nt = 0; nt < 4; ++nt) {
      const half4_t bq =
          *reinterpret_cast<const half4_t*>(&qkL[(nt * 16 + l15) * QKS + 16 + kg * 4]);
      const floatx4 z = {};
      qkreg[nt] = __builtin_amdgcn_mfma_f32_16x16x16f16(aq, bq, z, 0, 0, 0);
    }
#pragma unroll
    for (int nt = 0; nt < 8; ++nt) {
      const floatx4 z = {};
      const floatx4 cr = __builtin_amdgcn_mfma_f32_16x16x16f16(aq, brq[nt], z, 0, 0, 0);
#pragma unroll
      for (int r = 0; r < 4; ++r)
        M1[(wid * 16 + kg * 4 + r) * M1S + nt * 16 + l15] = f2hb(cr[r]);
    }
#pragma unroll
    for (int nt = 0; nt < 8; ++nt) {
      const floatx4 z = {};
      const floatx4 cr = __builtin_amdgcn_mfma_f32_16x16x16f16(ak, brk[nt], z, 0, 0, 0);
#pragma unroll
      for (int r = 0; r < 4; ++r)
        M2[(wid * 16 + kg * 4 + r) * M1S + nt * 16 + l15] = f2hb(cr[r]);
    }
  }
  __syncthreads();

  // ---- phase 3a: gather M1/M2, assemble S in registers; prefetch V ----
  const uint4 vld = *reinterpret_cast<const uint4*>(
      &qkv_h[((size_t)b * 512 + g * 64 + 32 + (tid >> 3)) * 64 + (tid & 7) * 8]);
  float sreg[4][4];
  {
    const float4 bf = *reinterpret_cast<const float4*>(&bnsF[g * 4]);
#pragma unroll
    for (int nt = 0; nt < 4; ++nt) {
      const int j = nt * 16 + l15;
#pragma unroll
      for (int r = 0; r < 4; ++r) {
        const int i = wid * 16 + kg * 4 + r;
        const int d = i - j + 63;  // 0..126
        const float qr = hb2f(M1[i * M1S + d]);
        const float kr = hb2f(M2[j * M1S + 126 - d]);
        sreg[nt][r] = fmaf(bf.x, qkreg[nt][r], fmaf(bf.y, qr, fmaf(bf.z, kr, bf.w)));
      }
    }
  }
  __syncthreads();  // M1/M2 dead; Pb/Pp/Vb overlay live

  // ---- phase 3b: in-register softmax; write Pb, Pp (+zero complement), Vb ----
  float sm[4];
#pragma unroll
  for (int r = 0; r < 4; ++r) {
    float m = fmaxf(fmaxf(sreg[0][r], sreg[1][r]), fmaxf(sreg[2][r], sreg[3][r]));
    m = fmaxf(m, __shfl_xor(m, 1));
    m = fmaxf(m, __shfl_xor(m, 2));
    m = fmaxf(m, __shfl_xor(m, 4));
    m = fmaxf(m, __shfl_xor(m, 8));
    float s = 0.f;
#pragma unroll
    for (int nt = 0; nt < 4; ++nt) {
      sreg[nt][r] = __expf(sreg[nt][r] - m);
      s += sreg[nt][r];
    }
    s += __shfl_xor(s, 1);
    s += __shfl_xor(s, 2);
    s += __shfl_xor(s, 4);
    s += __shfl_xor(s, 8);
    sm[r] = s;
  }
#pragma unroll
  for (int r = 0; r < 4; ++r) {
    const int i = wid * 16 + kg * 4 + r;
#pragma unroll
    for (int nt = 0; nt < 4; ++nt) {
      const int j = nt * 16 + l15;
      const unsigned short pv = f2hb(sreg[nt][r]);
      Pb[i * PBS + j] = pv;
      Pp[i * PPS + i + 63 - j] = pv;
    }
#pragma unroll
    for (int e = 0; e < 4; ++e) {  // zero complement of [i, i+63] in [0,128)
      const int z = l15 * 4 + e;
      const int t = (z < i) ? z : z + 64;
      Pp[i * PPS + t] = 0;
    }
  }
  {
    *reinterpret_cast<uint4*>(&Vb[(tid >> 3) * PBS + (tid & 7) * 8]) = vld;
  }
  __syncthreads();

  // ---- phase 5: sv / sve MFMAs (fp16 K=32) ----
  floatx4 sva[2] = {}, svea[2] = {};
#pragma unroll
  for (int kk = 0; kk < 2; ++kk) {
    const half8_t pa =
        *reinterpret_cast<const half8_t*>(&Pb[(wid * 16 + l15) * PBS + kk * 32 + kg * 8]);
#pragma unroll
    for (int nt = 0; nt < 2; ++nt) {
      const half8_t vb =
          *reinterpret_cast<const half8_t*>(&Vb[(nt * 16 + l15) * PBS + kk * 32 + kg * 8]);
      sva[nt] = __builtin_amdgcn_mfma_f32_16x16x32_f16(pa, vb, sva[nt], 0, 0, 0);
    }
  }
#pragma unroll
  for (int kk = 0; kk < 4; ++kk) {
    const half8_t pp =
        *reinterpret_cast<const half8_t*>(&Pp[(wid * 16 + l15) * PPS + kk * 32 + kg * 8]);
#pragma unroll
    for (int nt = 0; nt < 2; ++nt) {
      const half8_t rb =
          *reinterpret_cast<const half8_t*>(&relV[(nt * 16 + l15) * 128 + kk * 32 + kg * 8]);
      svea[nt] = __builtin_amdgcn_mfma_f32_16x16x32_f16(pp, rb, svea[nt], 0, 0, 0);
    }
  }
  __syncthreads();  // all Pb/Pp/Vb reads done; Sout overlays

  // ---- epilogue: BN (precomputed coeffs) + out-tile + coalesced store ----
#pragma unroll
  for (int nt = 0; nt < 2; ++nt) {
    const int c = nt * 16 + l15;
    const int ch = ((g << 5) + c) * 2;
    const float2 scv = *reinterpret_cast<const float2*>(&bnoSc[ch]);
    const float2 shv = *reinterpret_cast<const float2*>(&bnoSh[ch]);
#pragma unroll
    for (int r = 0; r < 4; ++r) {
      const int i = wid * 16 + kg * 4 + r;
      const float inv = 1.0f / sm[r];
      Sout[c * OTS + i] =
          fmaf(scv.x, sva[nt][r] * inv, shv.x) + fmaf(scv.y, svea[nt][r] * inv, shv.y);
    }
  }
  __syncthreads();
  {
    const size_t outbase = (size_t)b * 64;
#pragma unroll
    for (int r = 0; r < 8; ++r) {
      const int idx = tid + r * 256;
      const int cc = idx >> 6, ii = idx & 63;
      out[(size_t)((g << 5) + cc) * 32768 + outbase + ii] = Sout[cc * OTS + ii];
    }
  }
}

extern "C" void kernel_launch(void* const* d_in, const int* in_sizes, int n_in,
                              void* d_out, int out_size, void* d_ws, size_t ws_size,
                              hipStream_t stream) {
  const float* x = (const float*)d_in[0];         // (1,256,16,32,64)
  const float* qkv_w = (const float*)d_in[1];     // (512,256)
  const float* relative = (const float*)d_in[2];  // (64,127)
  const float* bn_qkv = (const float*)d_in[3];    // (4,512)
  const float* bn_sim = (const float*)d_in[4];    // (4,24)
  const float* bn_out = (const float*)d_in[5];    // (4,512)
  float* out = (float*)d_out;                     // (256, 512, 64) as [op][b][h]
  char* ws = (char*)d_ws;

  k_qkv_gemm<<<4096, 256, 0, stream>>>(x, qkv_w, bn_qkv, relative, bn_sim, bn_out, ws);
  k_attn<<<4096, 256, 0, stream>>>(ws, out);
}